// Round 9
// baseline (88.672 us; speedup 1.0000x reference)
//
#include <hip/hip_runtime.h>
#include <math.h>

#define B 8
#define N 2048
#define D 3072
#define NCHUNK 128
#define CHUNK (N / NCHUNK)        // 16 training rows per chunk/block
#define K2_BPB (D / 256)          // 12 blocks per batch in K2

// ---- device helpers ----------------------------------------------------

struct Scalars {
    float state_scale;  // sqrt(1 + var_tilde)
    float inv_2vt;      // 1 / (2 * var_tilde)
    float alpha;
    float inv_sigma;
};

__device__ inline Scalars compute_scalars(const float* __restrict__ ng) {
    float gamma = ng[0] * 25.0f - 15.0f;
    float var_tilde = expf(-gamma);
    float variance = 1.0f / (1.0f + expf(gamma));   // sigmoid(-gamma)
    Scalars s;
    s.state_scale = sqrtf(1.0f + var_tilde);
    s.inv_2vt     = 0.5f / var_tilde;
    s.alpha       = sqrtf(1.0f - variance);
    s.inv_sigma   = 1.0f / sqrtf(variance);
    return s;
}

__device__ inline void fma4(float4& a, float p, const float4& t) {
    a.x = fmaf(p, t.x, a.x);
    a.y = fmaf(p, t.y, a.y);
    a.z = fmaf(p, t.z, a.z);
    a.w = fmaf(p, t.w, a.w);
}

// ---- K1: per-chunk flash-softmax partial --------------------------------
// block = chunk c (16 rows). Phase A: sse[j][b] (diff^2, f64-assisted).
// Phase B: chunk-local min/exp/denominator. Phase C: weighted sum of the
// SAME train rows (L2-hot re-read) -> partials[c][b][d]; stats cmin/cden.
// No cross-block communication at all.

__global__ __launch_bounds__(256) void k_chunk(
        const float* __restrict__ in, const float* __restrict__ ng,
        const float* __restrict__ mask, const float* __restrict__ train,
        float* __restrict__ partials, float* __restrict__ cmin,
        float* __restrict__ cden) {
    const int tid = threadIdx.x;
    const int c   = blockIdx.x;
    const int n0  = c * CHUNK;
    const Scalars sc = compute_scalars(ng);

    // register-resident pre-scaled masked input slice
    float4 sm[3][B];
    float4 m4[3];
#pragma unroll
    for (int k = 0; k < 3; ++k) {
        const int d = (tid + k * 256) * 4;
        m4[k] = *(const float4*)(mask + d);
#pragma unroll
        for (int b = 0; b < B; ++b) {
            const float4 s = *(const float4*)(in + b * D + d);
            sm[k][b].x = s.x * sc.state_scale * m4[k].x;
            sm[k][b].y = s.y * sc.state_scale * m4[k].y;
            sm[k][b].z = s.z * sc.state_scale * m4[k].z;
            sm[k][b].w = s.w * sc.state_scale * m4[k].w;
        }
    }

    __shared__ float red[CHUNK][4][B];   // per-wave partials
    __shared__ float sse_s[CHUNK][B];
    __shared__ float u_s[CHUNK][B];      // exp weights (row-broadcast reads)
    __shared__ float smin[B];
    const int wave = tid >> 6, lane = tid & 63;

    // ---- Phase A: sse for the chunk's 16 rows ----
#pragma unroll 1
    for (int j = 0; j < CHUNK; ++j) {
        const float* trow = train + (size_t)(n0 + j) * D;
        double acc[B];
#pragma unroll
        for (int b = 0; b < B; ++b) acc[b] = 0.0;

#pragma unroll
        for (int k = 0; k < 3; ++k) {
            const int d = (tid + k * 256) * 4;
            const float4 t = *(const float4*)(trow + d);
            float4 tm;
            tm.x = t.x * m4[k].x;
            tm.y = t.y * m4[k].y;
            tm.z = t.z * m4[k].z;
            tm.w = t.w * m4[k].w;
#pragma unroll
            for (int b = 0; b < B; ++b) {
                float dx = sm[k][b].x - tm.x;
                float dy = sm[k][b].y - tm.y;
                float dz = sm[k][b].z - tm.z;
                float dw = sm[k][b].w - tm.w;
                float s4 = fmaf(dx, dx, fmaf(dy, dy, fmaf(dz, dz, dw * dw)));
                acc[b] += (double)s4;
            }
        }
#pragma unroll
        for (int b = 0; b < B; ++b) {
            float f = (float)acc[b];
            for (int off = 32; off; off >>= 1)
                f += __shfl_down(f, off);
            if (lane == 0) red[j][wave][b] = f;
        }
    }
    __syncthreads();
    if (tid < CHUNK * B) {
        const int j = tid >> 3, b = tid & 7;
        sse_s[j][b] = red[j][0][b] + red[j][1][b] + red[j][2][b] + red[j][3][b];
    }
    __syncthreads();

    // ---- Phase B: chunk-local softmax stats ----
    if (tid < B) {
        float m = sse_s[0][tid];
#pragma unroll
        for (int j = 1; j < CHUNK; ++j) m = fminf(m, sse_s[j][tid]);
        smin[tid] = m;
    }
    __syncthreads();
    if (tid < CHUNK * B) {
        const int j = tid >> 3, b = tid & 7;
        u_s[j][b] = expf((smin[b] - sse_s[j][b]) * sc.inv_2vt);  // <= 1
    }
    __syncthreads();
    if (tid < B) {
        float s = 0.0f;
#pragma unroll
        for (int j = 0; j < CHUNK; ++j) s += u_s[j][tid];
        cden[c * B + tid] = s;
        cmin[c * B + tid] = smin[tid];
    }

    // ---- Phase C: weighted sum over the chunk (train re-read, L2-hot) ----
#pragma unroll
    for (int k = 0; k < 3; ++k) {
        const int d = (tid + k * 256) * 4;
        float4 acc[B];
#pragma unroll
        for (int b = 0; b < B; ++b) acc[b] = make_float4(0.f, 0.f, 0.f, 0.f);
#pragma unroll
        for (int j = 0; j < CHUNK; ++j) {
            const float4 t  = *(const float4*)(train + (size_t)(n0 + j) * D + d);
            const float4 u0 = *(const float4*)&u_s[j][0];
            const float4 u1 = *(const float4*)&u_s[j][4];
            fma4(acc[0], u0.x, t); fma4(acc[1], u0.y, t);
            fma4(acc[2], u0.z, t); fma4(acc[3], u0.w, t);
            fma4(acc[4], u1.x, t); fma4(acc[5], u1.y, t);
            fma4(acc[6], u1.z, t); fma4(acc[7], u1.w, t);
        }
#pragma unroll
        for (int b = 0; b < B; ++b)
            *(float4*)(partials + ((size_t)(c * B + b)) * D + d) = acc[b];
    }
}

// ---- K2: global combine + epilogue --------------------------------------
// thread = one (b,d) output. M_b = max_c ll_cb; denoised =
// sum_c e^{ll-M} partial / sum_c e^{ll-M} den. cmin/cden loads are
// wave-uniform (L2 broadcast); partials loads coalesced per c.

__global__ __launch_bounds__(256) void k_combine(
        const float* __restrict__ in, const float* __restrict__ ng,
        const float* __restrict__ mask, const float* __restrict__ partials,
        const float* __restrict__ cmin, const float* __restrict__ cden,
        float* __restrict__ out) {
    const int tid = threadIdx.x;
    const int b   = blockIdx.x / K2_BPB;
    const int d   = (blockIdx.x % K2_BPB) * 256 + tid;
    const Scalars sc = compute_scalars(ng);

    float M = -INFINITY;
#pragma unroll 16
    for (int c = 0; c < NCHUNK; ++c)
        M = fmaxf(M, -cmin[c * B + b] * sc.inv_2vt);

    float s = 0.0f, den = 0.0f;
#pragma unroll 16
    for (int c = 0; c < NCHUNK; ++c) {
        const float w = expf(-cmin[c * B + b] * sc.inv_2vt - M);
        den = fmaf(w, cden[c * B + b], den);
        s   = fmaf(w, partials[((size_t)(c * B + b)) * D + d], s);
    }

    const int i = b * D + d;
    out[i] = (in[i] - sc.alpha * (s / den)) * sc.inv_sigma * mask[d];
}

// ---- launch --------------------------------------------------------------

extern "C" void kernel_launch(void* const* d_in, const int* in_sizes, int n_in,
                              void* d_out, int out_size, void* d_ws, size_t ws_size,
                              hipStream_t stream) {
    const float* in    = (const float*)d_in[0];   // [8,3,32,32]
    const float* ng    = (const float*)d_in[1];   // [1]
    const float* mask  = (const float*)d_in[2];   // [3,32,32]
    const float* train = (const float*)d_in[3];   // [2048,3,32,32]
    float* out = (float*)d_out;

    float* ws       = (float*)d_ws;
    float* partials = ws;                                    // NCHUNK*B*D (12.6 MB)
    float* cmin     = ws + (size_t)NCHUNK * B * D;           // NCHUNK*B
    float* cden     = cmin + NCHUNK * B;                     // NCHUNK*B

    k_chunk<<<NCHUNK, 256, 0, stream>>>(in, ng, mask, train,
                                        partials, cmin, cden);
    k_combine<<<B * K2_BPB, 256, 0, stream>>>(in, ng, mask, partials,
                                              cmin, cden, out);
}

// Round 10
// 38.925 us; speedup vs baseline: 2.2780x; 2.2780x over previous
//
#include <hip/hip_runtime.h>
#include <math.h>

#define B 8
#define N 2048
#define D 3072
#define K1_BLOCKS 512
#define NPB (N / K1_BLOCKS)       // 4 training rows per K1 block
#define OUT_BLOCKS ((B * D) / 256)// 96 blocks init out in K1

#define NGROUP 32                 // K2 row-groups (64 rows each)
#define GROWS (N / NGROUP)        // 64
#define NSLICE 12                 // K2 d-slices of 256 floats
#define K2_BLOCKS (NGROUP * NSLICE)

// ---- device helpers ----------------------------------------------------

struct Scalars {
    float state_scale;  // sqrt(1 + var_tilde)
    float inv_2vt;      // 1 / (2 * var_tilde)
    float alpha;
    float inv_sigma;
};

__device__ inline Scalars compute_scalars(const float* __restrict__ ng) {
    float gamma = ng[0] * 25.0f - 15.0f;
    float var_tilde = expf(-gamma);
    float variance = 1.0f / (1.0f + expf(gamma));   // sigmoid(-gamma)
    Scalars s;
    s.state_scale = sqrtf(1.0f + var_tilde);
    s.inv_2vt     = 0.5f / var_tilde;
    s.alpha       = sqrtf(1.0f - variance);
    s.inv_sigma   = 1.0f / sqrtf(variance);
    return s;
}

// ---- K1: sse[b][n] + out init ------------------------------------------
// 512 blocks x 256 threads, 4 rows/block (round-2 structure, absmax 0.0).
// Blocks 0..95 additionally write out = in * inv_sigma * mask.

__global__ __launch_bounds__(256, 2) void k_sse(
        const float* __restrict__ in, const float* __restrict__ ng,
        const float* __restrict__ mask, const float* __restrict__ train,
        float* __restrict__ sse_out, float* __restrict__ out) {
    const int tid = threadIdx.x;
    const int bid = blockIdx.x;
    const int n0  = bid * NPB;
    const Scalars sc = compute_scalars(ng);

    // register-resident pre-scaled masked input slice
    float4 sm[3][B];
    float4 m4[3];
#pragma unroll
    for (int k = 0; k < 3; ++k) {
        const int d = (tid + k * 256) * 4;
        m4[k] = *(const float4*)(mask + d);
#pragma unroll
        for (int b = 0; b < B; ++b) {
            const float4 s = *(const float4*)(in + b * D + d);
            sm[k][b].x = s.x * sc.state_scale * m4[k].x;
            sm[k][b].y = s.y * sc.state_scale * m4[k].y;
            sm[k][b].z = s.z * sc.state_scale * m4[k].z;
            sm[k][b].w = s.w * sc.state_scale * m4[k].w;
        }
    }

    __shared__ float red[NPB][4][B];
    const int wave = tid >> 6, lane = tid & 63;

#pragma unroll
    for (int j = 0; j < NPB; ++j) {
        const float* trow = train + (size_t)(n0 + j) * D;
        double acc[B];
#pragma unroll
        for (int b = 0; b < B; ++b) acc[b] = 0.0;

#pragma unroll
        for (int k = 0; k < 3; ++k) {
            const int d = (tid + k * 256) * 4;
            const float4 t = *(const float4*)(trow + d);
            float4 tm;
            tm.x = t.x * m4[k].x;
            tm.y = t.y * m4[k].y;
            tm.z = t.z * m4[k].z;
            tm.w = t.w * m4[k].w;
#pragma unroll
            for (int b = 0; b < B; ++b) {
                float dx = sm[k][b].x - tm.x;
                float dy = sm[k][b].y - tm.y;
                float dz = sm[k][b].z - tm.z;
                float dw = sm[k][b].w - tm.w;
                float s4 = fmaf(dx, dx, fmaf(dy, dy, fmaf(dz, dz, dw * dw)));
                acc[b] += (double)s4;
            }
        }
#pragma unroll
        for (int b = 0; b < B; ++b) {
            float f = (float)acc[b];
            for (int off = 32; off; off >>= 1)
                f += __shfl_down(f, off);
            if (lane == 0) red[j][wave][b] = f;
        }
    }
    __syncthreads();
    if (tid < NPB * B) {
        const int j = tid >> 3, b = tid & 7;
        sse_out[b * N + (n0 + j)] =
            red[j][0][b] + red[j][1][b] + red[j][2][b] + red[j][3][b];
    }

    // out init: out = in * inv_sigma * mask
    if (bid < OUT_BLOCKS) {
        const int i = bid * 256 + tid;
        const int d = i % D;
        out[i] = in[i] * sc.inv_sigma * mask[d];
    }
}

// ---- K2: softmax-weighted scatter --------------------------------------
// grid = (32 row-groups x 12 d-slices). Each block: redundant global
// softmax stats from sse, normalized weights for its 64 rows (LDS),
// weighted train sum for its 256-float slice, atomicAdd into out.

__global__ __launch_bounds__(256) void k_scatter(
        const float* __restrict__ ng, const float* __restrict__ mask,
        const float* __restrict__ train, const float* __restrict__ sse,
        float* __restrict__ out) {
    const int tid = threadIdx.x;
    const int g   = blockIdx.x / NSLICE;         // row-group
    const int s   = blockIdx.x % NSLICE;         // d-slice
    const int jr  = tid >> 6;                    // row strip 0..3
    const int dl  = tid & 63;                    // d-quad lane
    const int wave = jr, lane = dl;
    const Scalars sc = compute_scalars(ng);

    __shared__ float u_s[GROWS][B];              // group weights (normalized)
    __shared__ float redm[4][B];
    __shared__ float stat[B];                    // min, then inv-den scale
    __shared__ float red4[4 * B * 64 * 4];       // [jr][b][dl] float4

    const float4* sse4 = (const float4*)sse;     // [b][512]

    // ---- pass 1: per-b global min of sse ----
    float mn[B];
#pragma unroll
    for (int b = 0; b < B; ++b) {
        float4 v0 = sse4[b * 512 + tid];
        float4 v1 = sse4[b * 512 + tid + 256];
        mn[b] = fminf(fminf(fminf(v0.x, v0.y), fminf(v0.z, v0.w)),
                      fminf(fminf(v1.x, v1.y), fminf(v1.z, v1.w)));
        for (int off = 32; off; off >>= 1)
            mn[b] = fminf(mn[b], __shfl_xor(mn[b], off));
    }
    if (lane == 0) {
#pragma unroll
        for (int b = 0; b < B; ++b) redm[wave][b] = mn[b];
    }
    __syncthreads();
#pragma unroll
    for (int b = 0; b < B; ++b)
        mn[b] = fminf(fminf(redm[0][b], redm[1][b]),
                      fminf(redm[2][b], redm[3][b]));
    __syncthreads();

    // ---- pass 2: den = sum exp((mn-sse)*iv); capture group rows ----
    float den[B];
#pragma unroll
    for (int b = 0; b < B; ++b) {
        den[b] = 0.0f;
#pragma unroll
        for (int k = 0; k < 2; ++k) {
            const int q = tid + k * 256;         // n-quad
            const float4 v = sse4[b * 512 + q];
            float e0 = expf((mn[b] - v.x) * sc.inv_2vt);
            float e1 = expf((mn[b] - v.y) * sc.inv_2vt);
            float e2 = expf((mn[b] - v.z) * sc.inv_2vt);
            float e3 = expf((mn[b] - v.w) * sc.inv_2vt);
            den[b] += (e0 + e1) + (e2 + e3);
            const int n = q * 4;                 // first n of quad
            const int j = n - g * GROWS;
            if (j >= 0 && j < GROWS) {           // quads never straddle groups
                u_s[j][b]     = e0;
                u_s[j + 1][b] = e1;
                u_s[j + 2][b] = e2;
                u_s[j + 3][b] = e3;
            }
        }
        for (int off = 32; off; off >>= 1)
            den[b] += __shfl_xor(den[b], off);
    }
    if (lane == 0) {
#pragma unroll
        for (int b = 0; b < B; ++b) redm[wave][b] = den[b];
    }
    __syncthreads();
    if (tid < B)
        stat[tid] = sc.alpha * sc.inv_sigma /
                    (redm[0][tid] + redm[1][tid] + redm[2][tid] + redm[3][tid]);
    __syncthreads();

    // normalize group weights: u = exp * alpha*inv_sigma/den
    for (int idx = tid; idx < GROWS * B; idx += 256) {
        const int j = idx >> 3, b = idx & 7;
        u_s[j][b] *= stat[b];
    }
    __syncthreads();

    // ---- main: weighted sum over the group's rows for this d-slice ----
    const int d = s * 256 + dl * 4;
    float4 acc[B];
#pragma unroll
    for (int b = 0; b < B; ++b) acc[b] = make_float4(0.f, 0.f, 0.f, 0.f);

#pragma unroll
    for (int jj = 0; jj < GROWS / 4; ++jj) {     // 16 iters
        const int j = jj * 4 + jr;
        const int n = g * GROWS + j;
        const float4 t = *(const float4*)(train + (size_t)n * D + d);
#pragma unroll
        for (int b = 0; b < B; ++b) {
            const float u = u_s[j][b];
            acc[b].x = fmaf(u, t.x, acc[b].x);
            acc[b].y = fmaf(u, t.y, acc[b].y);
            acc[b].z = fmaf(u, t.z, acc[b].z);
            acc[b].w = fmaf(u, t.w, acc[b].w);
        }
    }

    // LDS reduce across the 4 row strips, then atomic scatter
    float4* red4v = (float4*)red4;               // [jr][b][dl]
#pragma unroll
    for (int b = 0; b < B; ++b)
        red4v[(jr * B + b) * 64 + dl] = acc[b];
    __syncthreads();
    if (jr == 0) {
        const float4 m4 = *(const float4*)(mask + d);
#pragma unroll
        for (int b = 0; b < B; ++b) {
            float4 s0 = red4v[(0 * B + b) * 64 + dl];
            float4 s1 = red4v[(1 * B + b) * 64 + dl];
            float4 s2 = red4v[(2 * B + b) * 64 + dl];
            float4 s3 = red4v[(3 * B + b) * 64 + dl];
            float vx = (s0.x + s1.x) + (s2.x + s3.x);
            float vy = (s0.y + s1.y) + (s2.y + s3.y);
            float vz = (s0.z + s1.z) + (s2.z + s3.z);
            float vw = (s0.w + s1.w) + (s2.w + s3.w);
            float* o = out + b * D + d;
            unsafeAtomicAdd(o + 0, -m4.x * vx);
            unsafeAtomicAdd(o + 1, -m4.y * vy);
            unsafeAtomicAdd(o + 2, -m4.z * vz);
            unsafeAtomicAdd(o + 3, -m4.w * vw);
        }
    }
}

// ---- launch --------------------------------------------------------------

extern "C" void kernel_launch(void* const* d_in, const int* in_sizes, int n_in,
                              void* d_out, int out_size, void* d_ws, size_t ws_size,
                              hipStream_t stream) {
    const float* in    = (const float*)d_in[0];   // [8,3,32,32]
    const float* ng    = (const float*)d_in[1];   // [1]
    const float* mask  = (const float*)d_in[2];   // [3,32,32]
    const float* train = (const float*)d_in[3];   // [2048,3,32,32]
    float* out = (float*)d_out;

    float* sse = (float*)d_ws;                    // B*N floats

    k_sse<<<K1_BLOCKS, 256, 0, stream>>>(in, ng, mask, train, sse, out);
    k_scatter<<<K2_BLOCKS, 256, 0, stream>>>(ng, mask, train, sse, out);
}